// Round 5
// baseline (220.122 us; speedup 1.0000x reference)
//
#include <hip/hip_runtime.h>
#include <math.h>

#define PI_F 3.14159265358979323846f

// padded LDS index (+1 word per 32) -> breaks power-of-2 bank strides
__device__ __forceinline__ int PSI(int i) { return i + (i >> 5); }
// bit-reverse a 9-bit index, then pad (in-place DIF leaves X[rev9(p)] at position p)
__device__ __forceinline__ int RVP(int v) {
  int r = (int)(__brev((unsigned)v) >> 23);
  return r + (r >> 5);
}

// branchless DIF butterfly: own value (cr,ci) at g, partner (pr,pi) at g^d.
// u-side (g&d==0): new = own+partner. v-side: new = (partner-own)*e^{-i\theta}.
#define BFLY(cr, ci, pr, pi, vs, wx, wy) do {            \
    float sr_ = (vs) ? ((pr) - (cr)) : ((pr) + (cr));    \
    float si_ = (vs) ? ((pi) - (ci)) : ((pi) + (ci));    \
    float ex_ = (vs) ? (wx) : 1.0f;                      \
    float ey_ = (vs) ? (wy) : 0.0f;                      \
    (cr) = sr_ * ex_ + si_ * ey_;                        \
    (ci) = si_ * ex_ - sr_ * ey_;                        \
  } while (0)

// shuffle-exchange stage: d = pair distance, h = d/2 = thread xor mask.
// m0 = (2t mod d)*(256/d) indexes TW (theta = pi*m/256); odd-element twiddle =
// even twiddle rotated by pi/d (CH,SH compile-time consts).
#define SHUF_STAGE(d, h, CH, SH) do {                                   \
    float p0r = __shfl_xor(c0r, h); float p0i = __shfl_xor(c0i, h);     \
    float p1r = __shfl_xor(c1r, h); float p1i = __shfl_xor(c1i, h);     \
    bool vs = (t & (h)) != 0;                                           \
    int m0 = ((2 * t) & ((d) - 1)) * (256 / (d));                       \
    float w0x = TWc[m0], w0y = TWs[m0];                                 \
    float w1x = w0x * (CH) - w0y * (SH);                                \
    float w1y = w0y * (CH) + w0x * (SH);                                \
    BFLY(c0r, c0i, p0r, p0i, vs, w0x, w0y);                             \
    BFLY(c1r, c1i, p1r, p1i, vs, w1x, w1y);                             \
  } while (0)

// 512-pt in-place DIF FFT; thread t holds z[2t],z[2t+1] in (c0,c1).
// On exit Z LDS arrays hold result at padded in-place positions:
// value at position p (padded PSI(p)) is X[rev9(p)]. Ends with barrier.
__device__ __forceinline__ void fft512r(float& c0r, float& c0i, float& c1r, float& c1i,
                                        float* Zr, float* Zi,
                                        const float* TWc, const float* TWs, int t) {
  const int i0 = PSI(2 * t);   // PSI(2t+1) == i0+1 (2t even, no pad boundary)
  // ---- stage d=256 (LDS exchange, partner thread t^128)
  Zr[i0] = c0r; Zr[i0 + 1] = c1r;
  Zi[i0] = c0i; Zi[i0 + 1] = c1i;
  __syncthreads();
  {
    int pp = PSI((2 * t) ^ 256);
    float p0r = Zr[pp], p0i = Zi[pp];
    float p1r = Zr[pp + 1], p1i = Zi[pp + 1];
    bool vs = (t & 128) != 0;
    int m0 = (2 * t) & 255;
    float w0x = TWc[m0], w0y = TWs[m0];
    const float CH = 0.99992470183914450f, SH = 0.01227153828571993f;  // pi/256
    float w1x = w0x * CH - w0y * SH, w1y = w0y * CH + w0x * SH;
    BFLY(c0r, c0i, p0r, p0i, vs, w0x, w0y);
    BFLY(c1r, c1i, p1r, p1i, vs, w1x, w1y);
  }
  __syncthreads();                    // all partner reads done before rewrite
  // ---- stage d=128 (LDS exchange, partner thread t^64)
  Zr[i0] = c0r; Zr[i0 + 1] = c1r;
  Zi[i0] = c0i; Zi[i0 + 1] = c1i;
  __syncthreads();
  {
    int pp = PSI((2 * t) ^ 128);
    float p0r = Zr[pp], p0i = Zi[pp];
    float p1r = Zr[pp + 1], p1i = Zi[pp + 1];
    bool vs = (t & 64) != 0;
    int m0 = ((2 * t) & 127) * 2;
    float w0x = TWc[m0], w0y = TWs[m0];
    const float CH = 0.99969881869620420f, SH = 0.02454122852291229f;  // pi/128
    float w1x = w0x * CH - w0y * SH, w1y = w0y * CH + w0x * SH;
    BFLY(c0r, c0i, p0r, p0i, vs, w0x, w0y);
    BFLY(c1r, c1i, p1r, p1i, vs, w1x, w1y);
  }
  // ---- stages d=64..2 via intra-wave shuffles
  SHUF_STAGE(64, 32, 0.99879545620517240f, 0.04906767432741802f);  // pi/64
  SHUF_STAGE(32, 16, 0.99518472667219690f, 0.09801714032956060f);  // pi/32
  SHUF_STAGE(16, 8,  0.98078528040323040f, 0.19509032201612825f);  // pi/16
  SHUF_STAGE(8, 4,   0.92387953251128670f, 0.38268343236508980f);  // pi/8
  SHUF_STAGE(4, 2,   0.70710678118654750f, 0.70710678118654750f);  // pi/4
  SHUF_STAGE(2, 1,   0.0f, 1.0f);                                  // pi/2
  // ---- stage d=1 in registers (twiddle = 1)
  {
    float ar = c0r, ai = c0i;
    c0r = ar + c1r; c0i = ai + c1i;
    c1r = ar - c1r; c1i = ai - c1i;
  }
  __syncthreads();                    // all d=128 reads done before write-out
  Zr[i0] = c0r; Zr[i0 + 1] = c1r;
  Zi[i0] = c0i; Zi[i0 + 1] = c1i;
  __syncthreads();
}

// |X[k]|^2 of length-1024 real FFT from the packed-512 result in Z (bit-rev stored).
// UP[k] = (cos,sin)(pi*k/512).
__device__ __forceinline__ float unpack_pwr(const float* Zr, const float* Zi,
                                            const float* UPc, const float* UPs, int k) {
  int kk = k & 511, kr = (512 - k) & 511;
  int a = RVP(kk), c = RVP(kr);
  float zr = Zr[a], zi = Zi[a];
  float ur = Zr[c], ui = Zi[c];
  float Er = 0.5f * (zr + ur), Ei = 0.5f * (zi - ui);
  float Or = 0.5f * (zi + ui), Oi = 0.5f * (ur - zr);
  float wx = UPc[k], wy = UPs[k];
  float re = Er + wx * Or + wy * Oi;
  float im = Ei + wx * Oi - wy * Or;
  return re * re + im * im;
}

__device__ __forceinline__ float unpack_re(const float* Zr, const float* Zi,
                                           const float* UPc, const float* UPs, int k) {
  int kk = k & 511, kr = (512 - k) & 511;
  int a = RVP(kk), c = RVP(kr);
  float zr = Zr[a], zi = Zi[a];
  float ur = Zr[c], ui = Zi[c];
  float Er = 0.5f * (zr + ur);
  float Or = 0.5f * (zi + ui), Oi = 0.5f * (ur - zr);
  float wx = UPc[k], wy = UPs[k];
  return Er + wx * Or + wy * Oi;
}

// tables in d_ws: TWc[256] TWs[256] UPc[513] UPs[513] = 1538 floats
__global__ __launch_bounds__(256) void init_tables(float* __restrict__ w) {
  int i = blockIdx.x * 256 + threadIdx.x;
  if (i < 256) {
    float sn, cs; sincosf((PI_F / 256.0f) * (float)i, &sn, &cs);
    w[i] = cs; w[256 + i] = sn;
  } else if (i < 769) {
    int k = i - 256;
    float sn, cs; sincosf((PI_F / 512.0f) * (float)k, &sn, &cs);
    w[512 + k] = cs; w[1025 + k] = sn;
  }
}

__global__ __launch_bounds__(256)
void cheaptrick_kernel(const float* __restrict__ x, const float* __restrict__ f0g,
                       float* __restrict__ out, int Tlen, int Nfr,
                       const float* __restrict__ tw) {
  __shared__ float Zr[528], Zi[528];      // padded 512
  __shared__ float ps[530];               // padded 513
  __shared__ float C[642];
  __shared__ float red[16];
  __shared__ float TWc[256], TWs[256];
  __shared__ float UPc[513], UPs[513];

  const int t = threadIdx.x;
  const int blk = blockIdx.x;
  const int b = blk / Nfr;
  const int n = blk - b * Nfr;
  const int lane = t & 63, wave = t >> 6;
  const float RATE = 15.625f;

  // ---- load twiddle tables (precomputed in ws; fallback computes)
  if (tw) {
    TWc[t] = tw[t];             TWs[t] = tw[256 + t];
    UPc[t] = tw[512 + t];       UPs[t] = tw[1025 + t];
    UPc[t + 257] = tw[769 + t]; UPs[t + 257] = tw[1282 + t];
    if (t == 0) { UPc[256] = tw[768]; UPs[256] = tw[1281]; }
  } else {
    float sn, cs;
    sincosf((PI_F / 256.0f) * (float)t, &sn, &cs); TWc[t] = cs; TWs[t] = sn;
    sincosf((PI_F / 512.0f) * (float)t, &sn, &cs); UPc[t] = cs; UPs[t] = sn;
    sincosf((PI_F / 512.0f) * (float)(t + 257), &sn, &cs); UPc[t + 257] = cs; UPs[t + 257] = sn;
    if (t == 0) { UPc[256] = 0.0f; UPs[256] = 1.0f; }
  }

  float f0v = f0g[blk];
  const float F_MIN = 3.0f * 16000.0f / 1021.0f;
  if (f0v <= F_MIN) f0v = 500.0f;

  // ---- windowed waveform: thread t owns contiguous samples 4t..4t+3
  float half_len = rintf(24000.0f / f0v);
  const int center = n * 80;
  const float* xb = x + (size_t)b * (size_t)Tlen;
  const int s0 = center - 512 + 4 * t;
  float xq[4];
  if (s0 >= 0 && s0 + 3 < Tlen) {
    const float4 f4 = *reinterpret_cast<const float4*>(xb + s0);
    xq[0] = f4.x; xq[1] = f4.y; xq[2] = f4.z; xq[3] = f4.w;
  } else {
    xq[0] = xb[min(max(s0, 0), Tlen - 1)];
    xq[1] = xb[min(max(s0 + 1, 0), Tlen - 1)];
    xq[2] = xb[min(max(s0 + 2, 0), Tlen - 1)];
    xq[3] = xb[min(max(s0 + 3, 0), Tlen - 1)];
  }
  float wv[4], wd[4];
  float sw = 0.f, swin = 0.f;
#pragma unroll
  for (int q = 0; q < 4; ++q) {
    float fb = (float)(4 * t + q - 512);
    float msk = (fabsf(fb) <= half_len) ? 1.0f : 0.0f;
    float win = (0.5f * __cosf(PI_F * (fb / 24000.0f) * f0v) + 0.5f) * msk;
    float wval = xq[q] * win;
    wd[q] = win; wv[q] = wval;
    sw += wval; swin += win;
  }
#pragma unroll
  for (int off = 32; off > 0; off >>= 1) {
    sw += __shfl_down(sw, off);
    swin += __shfl_down(swin, off);
  }
  if (lane == 0) { red[wave] = sw; red[4 + wave] = swin; }
  __syncthreads();
  float mf = (red[0] + red[1] + red[2] + red[3]) / (red[4] + red[5] + red[6] + red[7]);

  // pack z[2t]=w[4t]+i w[4t+1], z[2t+1]=w[4t+2]+i w[4t+3] directly in registers
  float c0r = wv[0] - wd[0] * mf, c0i = wv[1] - wd[1] * mf;
  float c1r = wv[2] - wd[2] * mf, c1i = wv[3] - wd[3] * mf;

  fft512r(c0r, c0i, c1r, c1i, Zr, Zi, TWc, TWs, t);

  // ---- power spectrum
  ps[PSI(t)] = unpack_pwr(Zr, Zi, UPc, UPs, t);
  ps[PSI(t + 256)] = unpack_pwr(Zr, Zi, UPc, UPs, t + 256);
  if (t == 0) ps[PSI(512)] = unpack_pwr(Zr, Zi, UPc, UPs, 512);
  __syncthreads();

  // ---- DC correction (k < f0/RATE <= 32)
  {
    float rep = 0.f;
    bool act = (t < 40);
    float kf = (float)t;
    if (act) {
      float pos = f0v / RATE - kf;
      int lo = (int)floorf(pos);
      lo = min(max(lo, 0), 511);
      float fr = pos - (float)lo;
      rep = ps[PSI(lo)] * (1.0f - fr) + ps[PSI(lo + 1)] * fr;
    }
    __syncthreads();
    if (act && kf * RATE < f0v) ps[PSI(t)] += rep;
  }
  __syncthreads();

  // ---- linear smoothing: cumsum of mirrored extension (641 vals)
  {
    const int ebase = 3 * t;
    float e0 = 0.f, e1 = 0.f, e2 = 0.f;
    {
      int e = ebase;
      if (e < 641)     { int j = e - 64;     j = j < 0 ? -j : j; if (j > 512) j = 1024 - j; e0 = ps[PSI(j)]; }
      if (e + 1 < 641) { int j = e + 1 - 64; j = j < 0 ? -j : j; if (j > 512) j = 1024 - j; e1 = ps[PSI(j)]; }
      if (e + 2 < 641) { int j = e + 2 - 64; j = j < 0 ? -j : j; if (j > 512) j = 1024 - j; e2 = ps[PSI(j)]; }
    }
    float psum = e0 + e1 + e2;
    float sc = psum;
#pragma unroll
    for (int off = 1; off < 64; off <<= 1) {
      float v = __shfl_up(sc, off);
      if (lane >= off) sc += v;
    }
    if (lane == 63) red[8 + wave] = sc;
    __syncthreads();
    float woff = 0.f;
#pragma unroll
    for (int w2 = 0; w2 < 4; ++w2) woff += (w2 < wave) ? red[8 + w2] : 0.f;
    float run = woff + (sc - psum);
    if (t == 0) C[0] = 0.f;
    if (ebase < 641)     { run += e0; C[ebase + 1] = RATE * run; }
    if (ebase + 1 < 641) { run += e1; C[ebase + 2] = RATE * run; }
    if (ebase + 2 < 641) { run += e2; C[ebase + 3] = RATE * run; }
  }
  __syncthreads();

  // ---- interp smoothed spectrum + log (overwrite ps with lp)
  {
    const float width = f0v * (2.0f / 3.0f);
    const float hwb = width * (1.0f / (2.0f * RATE));
    const float winv = 1.0f / width;
    float s0v, s1v, s2v = 1.f;
#pragma unroll
    for (int r = 0; r < 3; ++r) {
      int k = (r == 0) ? t : (r == 1) ? (t + 256) : 512;
      if (r == 2 && t != 0) break;
      float kf = (float)k;
      float qh = kf + hwb + 64.5f, ql = kf - hwb + 64.5f;
      int lh = (int)floorf(qh); lh = min(max(lh, 0), 640);
      int ll = (int)floorf(ql); ll = min(max(ll, 0), 640);
      float fh = qh - (float)lh, fl = ql - (float)ll;
      float vh = C[lh] * (1.f - fh) + C[lh + 1] * fh;
      float vl = C[ll] * (1.f - fl) + C[ll + 1] * fl;
      float v = (vh - vl) * winv;
      if (r == 0) s0v = v; else if (r == 1) s1v = v; else s2v = v;
    }
    ps[PSI(t)] = __logf(s0v);
    ps[PSI(t + 256)] = __logf(s1v);
    if (t == 0) ps[PSI(512)] = __logf(s2v);
  }
  __syncthreads();

  // ---- cepstrum FFT: even extension of lp, z[2t]=(e(4t),e(4t+1)), z[2t+1]=(e(4t+2),e(4t+3))
  if (t < 128) {
    int bse = 4 * t;
    c0r = ps[PSI(bse)];     c0i = ps[PSI(bse + 1)];
    c1r = ps[PSI(bse + 2)]; c1i = ps[PSI(bse + 3)];
  } else {
    int bse = 1024 - 4 * t;  // e(i)=1024-i for i>512; t=128 gives 512,511,510,509
    c0r = ps[PSI(bse)];     c0i = ps[PSI(bse - 1)];
    c1r = ps[PSI(bse - 2)]; c1i = ps[PSI(bse - 3)];
  }
  fft512r(c0r, c0i, c1r, c1i, Zr, Zi, TWc, TWs, t);

  // ---- lifter on cepstrum (= re(FFT)/1024), write lifted into ps
  {
    const float inv = 1.0f / 1024.0f;
    float l0, l1, l2 = 0.f;
#pragma unroll
    for (int r = 0; r < 3; ++r) {
      int k = (r == 0) ? t : (r == 1) ? (t + 256) : 512;
      if (r == 2 && t != 0) break;
      float cep = unpack_re(Zr, Zi, UPc, UPs, k) * inv;
      float z = f0v * ((float)k * (1.0f / 16000.0f));
      float pz = PI_F * z;
      float s = __sinf(pz);
      float sl = (k == 0) ? 1.0f : (s / pz);
      float cl = 1.0f + 0.6f * s * s;   // 1.3 - 0.3*cos(2pi z)
      float v = cep * sl * cl;
      if (r == 0) l0 = v; else if (r == 1) l1 = v; else l2 = v;
    }
    ps[PSI(t)] = l0; ps[PSI(t + 256)] = l1;
    if (t == 0) ps[PSI(512)] = l2;
  }
  __syncthreads();

  // ---- final hfft: even extension of lifted, FFT, real part
  if (t < 128) {
    int bse = 4 * t;
    c0r = ps[PSI(bse)];     c0i = ps[PSI(bse + 1)];
    c1r = ps[PSI(bse + 2)]; c1i = ps[PSI(bse + 3)];
  } else {
    int bse = 1024 - 4 * t;
    c0r = ps[PSI(bse)];     c0i = ps[PSI(bse - 1)];
    c1r = ps[PSI(bse - 2)]; c1i = ps[PSI(bse - 3)];
  }
  fft512r(c0r, c0i, c1r, c1i, Zr, Zi, TWc, TWs, t);

  {
    size_t ob = (size_t)blk * 513;
    out[ob + t]       = unpack_re(Zr, Zi, UPc, UPs, t);
    out[ob + t + 256] = unpack_re(Zr, Zi, UPc, UPs, t + 256);
    if (t == 0) out[ob + 512] = unpack_re(Zr, Zi, UPc, UPs, 512);
  }
}

extern "C" void kernel_launch(void* const* d_in, const int* in_sizes, int n_in,
                              void* d_out, int out_size, void* d_ws, size_t ws_size,
                              hipStream_t stream) {
  (void)n_in; (void)out_size;
  const float* x  = (const float*)d_in[0];
  const float* f0 = (const float*)d_in[1];
  float* out = (float*)d_out;
  int B = in_sizes[1] - in_sizes[0] / 80;
  if (B < 1) B = 1;
  int Tlen = in_sizes[0] / B;
  int Nfr  = in_sizes[1] / B;

  float* tw = nullptr;
  if (d_ws && ws_size >= 1538 * sizeof(float)) {
    tw = (float*)d_ws;
    hipLaunchKernelGGL(init_tables, dim3(4), dim3(256), 0, stream, tw);
  }
  hipLaunchKernelGGL(cheaptrick_kernel, dim3(in_sizes[1]), dim3(256), 0, stream,
                     x, f0, out, Tlen, Nfr, (const float*)tw);
}

// Round 8
// 212.929 us; speedup vs baseline: 1.0338x; 1.0338x over previous
//
#include <hip/hip_runtime.h>
#include <math.h>

#define PI_F 3.14159265358979323846f

// +1 pad word per 4 -> breaks the 4-way bank collisions of mid-stage scatter
// writes (addrs o = t + (t&~(m-1)), m=4/8/16) while keeping linear reads <=2-way.
__device__ __forceinline__ int P4(int i) { return i + (i >> 2); }

// ---- 512-point complex Stockham radix-2 FFT in LDS, twiddles from TW table.
// TW[m] = (cos, sin)(pi*m/256). Enters and exits with __syncthreads().
// All Ar/Ai/Br/Bi indices P4-padded (arrays sized 640).
__device__ __forceinline__ void fft512(float* Ar, float* Ai, float* Br, float* Bi,
                                       const float2* TW, int t) {
  float* xr = Ar; float* xi = Ai; float* yr = Br; float* yi = Bi;
#pragma unroll
  for (int s = 0; s < 9; ++s) {
    __syncthreads();
    const int m = 1 << s;
    float ar = xr[P4(t)],       ai = xi[P4(t)];
    float br = xr[P4(t + 256)], bi = xi[P4(t + 256)];
    float2 w = TW[t & ~(m - 1)];              // e^{-i*pi*(t&~(m-1))/256}
    int o = t + (t & ~(m - 1));               // = k + 2*j*m
    float sr = ar - br, si = ai - bi;
    yr[P4(o)] = ar + br;            yi[P4(o)] = ai + bi;
    yr[P4(o + m)] = sr * w.x + si * w.y;
    yi[P4(o + m)] = si * w.x - sr * w.y;
    float* tp;
    tp = xr; xr = yr; yr = tp;
    tp = xi; xi = yi; yi = tp;
  }
  __syncthreads();
}

// Real part of X[k] of the length-1024 real-input FFT whose packed 512-pt FFT
// is (Br,Bi) (P4-padded natural order). UP[k] = (cos, sin)(pi*k/512), k in [0,512].
__device__ __forceinline__ float unpack_re(const float* Br, const float* Bi,
                                           const float2* UP, int k) {
  int kk = k & 511, kr = (512 - k) & 511;
  float zr = Br[P4(kk)], zi = Bi[P4(kk)];
  float ur = Br[P4(kr)], ui = Bi[P4(kr)];
  float Er = 0.5f * (zr + ur);
  float Or = 0.5f * (zi + ui), Oi = 0.5f * (ur - zr);
  float2 w = UP[k];
  return Er + w.x * Or + w.y * Oi;
}

__device__ __forceinline__ float unpack_pwr(const float* Br, const float* Bi,
                                            const float2* UP, int k) {
  int kk = k & 511, kr = (512 - k) & 511;
  float zr = Br[P4(kk)], zi = Bi[P4(kk)];
  float ur = Br[P4(kr)], ui = Bi[P4(kr)];
  float Er = 0.5f * (zr + ur), Ei = 0.5f * (zi - ui);
  float Or = 0.5f * (zi + ui), Oi = 0.5f * (ur - zr);
  float2 w = UP[k];
  float re = Er + w.x * Or + w.y * Oi;
  float im = Ei + w.x * Oi - w.y * Or;
  return re * re + im * im;
}

// d_ws layout (as float2): [0,256) = TW (cos,sin)(pi*i/256); [256,769) = UP
// (cos,sin)(pi*k/512). 769 float2 = 1538 floats = 6152 bytes.
__global__ __launch_bounds__(256) void init_tables(float2* __restrict__ w2) {
  int i = blockIdx.x * 256 + threadIdx.x;
  if (i < 256) {
    float sn, cs; sincosf((PI_F / 256.0f) * (float)i, &sn, &cs);
    w2[i] = make_float2(cs, sn);
  } else if (i < 769) {
    int k = i - 256;
    float sn, cs; sincosf((PI_F / 512.0f) * (float)k, &sn, &cs);
    w2[i] = make_float2(cs, sn);
  }
}

__global__ __launch_bounds__(256)
void cheaptrick_kernel(const float* __restrict__ x, const float* __restrict__ f0g,
                       float* __restrict__ out, int Tlen, int Nfr,
                       const float2* __restrict__ twg) {
  __shared__ float Ar[640], Ai[640], Br[640], Bi[640];  // P4-padded 512
  __shared__ float ps[513];   // power spectrum -> log spectrum -> lifted cepstrum
  __shared__ float C[642];    // prepended-zero cumsum
  __shared__ float red[16];
  __shared__ float2 TW[256];  // e^{-i pi m/256}  (FFT twiddles, all stages)
  __shared__ float2 UP[513];  // e^{-i pi k/512}  (real-FFT unpack twiddles)

  const int t = threadIdx.x;
  const int blk = blockIdx.x;
  const int b = blk / Nfr;
  const int n = blk - b * Nfr;
  const int lane = t & 63, wave = t >> 6;
  const float RATE = 15.625f;

  // ---- load twiddle tables from ws (fallback computes in-kernel)
  if (twg) {
    TW[t] = twg[t];
    UP[t] = twg[256 + t];
    UP[t + 257] = twg[256 + t + 257];
    if (t == 0) UP[256] = twg[256 + 256];
  } else {
    float sn, cs;
    sincosf((PI_F / 256.0f) * (float)t, &sn, &cs);
    TW[t] = make_float2(cs, sn);
    sincosf((PI_F / 512.0f) * (float)t, &sn, &cs);
    UP[t] = make_float2(cs, sn);
    sincosf((PI_F / 512.0f) * (float)(t + 257), &sn, &cs);
    UP[t + 257] = make_float2(cs, sn);
    if (t == 0) UP[256] = make_float2(0.0f, 1.0f);
  }

  float f0v = f0g[blk];
  const float F_MIN = 3.0f * 16000.0f / 1021.0f;
  if (f0v <= F_MIN) f0v = 500.0f;

  // ---- windowed waveform: thread t owns samples {2t, 2t+1, 2t+512, 2t+513}
  float half_len = rintf(24000.0f / f0v);   // round-half-even matches jnp.round
  float wv[4], wd[4];
  float sw = 0.f, swin = 0.f;
  const int center = n * 80;
  const int ids[4] = {2 * t, 2 * t + 1, 2 * t + 512, 2 * t + 513};
#pragma unroll
  for (int q = 0; q < 4; ++q) {
    int base = ids[q] - 512;
    float fb = (float)base;
    float msk = (fabsf(fb) <= half_len) ? 1.0f : 0.0f;
    float win = (0.5f * __cosf(PI_F * (fb / 24000.0f) * f0v) + 0.5f) * msk;
    int src = center + base;
    src = min(max(src, 0), Tlen - 1);
    float wval = x[(size_t)b * (size_t)Tlen + src] * win;
    wd[q] = win; wv[q] = wval;
    sw += wval; swin += win;
  }
#pragma unroll
  for (int off = 32; off > 0; off >>= 1) {
    sw += __shfl_down(sw, off);
    swin += __shfl_down(swin, off);
  }
  if (lane == 0) { red[wave] = sw; red[4 + wave] = swin; }
  __syncthreads();
  float mf = (red[0] + red[1] + red[2] + red[3]) / (red[4] + red[5] + red[6] + red[7]);

  // pack z[m] = w[2m] + i*w[2m+1] into (Ar,Ai)
  Ar[P4(t)]       = wv[0] - wd[0] * mf;
  Ai[P4(t)]       = wv[1] - wd[1] * mf;
  Ar[P4(t + 256)] = wv[2] - wd[2] * mf;
  Ai[P4(t + 256)] = wv[3] - wd[3] * mf;

  fft512(Ar, Ai, Br, Bi, TW, t);

  // ---- power spectrum |rfft|^2, k in [0,513)
  {
    float p0 = unpack_pwr(Br, Bi, UP, t);
    float p1 = unpack_pwr(Br, Bi, UP, t + 256);
    float p2 = (t == 0) ? unpack_pwr(Br, Bi, UP, 512) : 0.f;
    ps[t] = p0; ps[t + 256] = p1;
    if (t == 0) ps[512] = p2;
  }
  __syncthreads();

  // ---- DC correction (only k < f0/RATE <= 32 matter)
  {
    float rep = 0.f;
    bool act = (t < 40);
    float kf = (float)t;
    if (act) {
      float pos = f0v / RATE - kf;
      int lo = (int)floorf(pos);
      lo = min(max(lo, 0), 511);
      float fr = pos - (float)lo;
      rep = ps[lo] * (1.0f - fr) + ps[lo + 1] * fr;
    }
    __syncthreads();
    if (act && kf * RATE < f0v) ps[t] += rep;
  }
  __syncthreads();

  // ---- linear smoothing: cumsum of mirrored extension (641 vals), then interp
  {
    const int ebase = 3 * t;
    float e0 = 0.f, e1 = 0.f, e2 = 0.f;
    {
      int e = ebase;
      if (e < 641)     { int j = e - 64;     j = j < 0 ? -j : j; if (j > 512) j = 1024 - j; e0 = ps[j]; }
      if (e + 1 < 641) { int j = e + 1 - 64; j = j < 0 ? -j : j; if (j > 512) j = 1024 - j; e1 = ps[j]; }
      if (e + 2 < 641) { int j = e + 2 - 64; j = j < 0 ? -j : j; if (j > 512) j = 1024 - j; e2 = ps[j]; }
    }
    float psum = e0 + e1 + e2;
    float sc = psum;
#pragma unroll
    for (int off = 1; off < 64; off <<= 1) {
      float v = __shfl_up(sc, off);
      if (lane >= off) sc += v;
    }
    if (lane == 63) red[8 + wave] = sc;
    __syncthreads();
    float woff = 0.f;
#pragma unroll
    for (int w2 = 0; w2 < 4; ++w2) woff += (w2 < wave) ? red[8 + w2] : 0.f;
    float run = woff + (sc - psum);    // exclusive prefix for this chunk
    if (t == 0) C[0] = 0.f;
    if (ebase < 641)     { run += e0; C[ebase + 1] = RATE * run; }
    if (ebase + 1 < 641) { run += e1; C[ebase + 2] = RATE * run; }
    if (ebase + 2 < 641) { run += e2; C[ebase + 3] = RATE * run; }
  }
  __syncthreads();

  // ---- interp smoothed spectrum, take log  (overwrite ps with lp)
  {
    const float width = f0v * (2.0f / 3.0f);
    const float hwb = width * (1.0f / (2.0f * RATE));
    const float winv = 1.0f / width;
    float s0, s1, s2 = 1.f;
#pragma unroll
    for (int r = 0; r < 3; ++r) {
      int k = (r == 0) ? t : (r == 1) ? (t + 256) : 512;
      if (r == 2 && t != 0) break;
      float kf = (float)k;
      float qh = kf + hwb + 64.5f, ql = kf - hwb + 64.5f;
      int lh = (int)floorf(qh); lh = min(max(lh, 0), 640);
      int ll = (int)floorf(ql); ll = min(max(ll, 0), 640);
      float fh = qh - (float)lh, fl = ql - (float)ll;
      float vh = C[lh] * (1.f - fh) + C[lh + 1] * fh;
      float vl = C[ll] * (1.f - fl) + C[ll + 1] * fl;
      float v = (vh - vl) * winv;
      if (r == 0) s0 = v; else if (r == 1) s1 = v; else s2 = v;
    }
    ps[t] = __logf(s0);
    ps[t + 256] = __logf(s1);
    if (t == 0) ps[512] = __logf(s2);
  }
  __syncthreads();

  // ---- cepstrum = irfft(lp): FFT of even extension, real part / 1024
  Ar[P4(t)]       = ps[2 * t];
  Ai[P4(t)]       = ps[2 * t + 1];
  Ar[P4(t + 256)] = ps[(2 * t + 512) <= 512 ? (2 * t + 512) : (1024 - (2 * t + 512))];
  Ai[P4(t + 256)] = ps[1024 - (2 * t + 513)];
  fft512(Ar, Ai, Br, Bi, TW, t);

  // ---- lifter, write lifted cepstrum into ps
  {
    const float inv = 1.0f / 1024.0f;
    float l0, l1, l2 = 0.f;
#pragma unroll
    for (int r = 0; r < 3; ++r) {
      int k = (r == 0) ? t : (r == 1) ? (t + 256) : 512;
      if (r == 2 && t != 0) break;
      float cep = unpack_re(Br, Bi, UP, k) * inv;
      float z = f0v * ((float)k * (1.0f / 16000.0f));
      float pz = PI_F * z;
      float s = __sinf(pz);
      float sl = (k == 0) ? 1.0f : (s / pz);
      float cl = 1.0f + 0.6f * s * s;   // 1.3 - 0.3*cos(2pi z), cos(2a)=1-2sin^2(a)
      float v = cep * sl * cl;
      if (r == 0) l0 = v; else if (r == 1) l1 = v; else l2 = v;
    }
    ps[t] = l0; ps[t + 256] = l1;
    if (t == 0) ps[512] = l2;
  }
  __syncthreads();

  // ---- final hfft = 1024 * irfft(lifted): FFT of even extension, real part
  Ar[P4(t)]       = ps[2 * t];
  Ai[P4(t)]       = ps[2 * t + 1];
  Ar[P4(t + 256)] = ps[(2 * t + 512) <= 512 ? (2 * t + 512) : (1024 - (2 * t + 512))];
  Ai[P4(t + 256)] = ps[1024 - (2 * t + 513)];
  fft512(Ar, Ai, Br, Bi, TW, t);

  {
    size_t ob = (size_t)blk * 513;
    out[ob + t]       = unpack_re(Br, Bi, UP, t);
    out[ob + t + 256] = unpack_re(Br, Bi, UP, t + 256);
    if (t == 0) out[ob + 512] = unpack_re(Br, Bi, UP, 512);
  }
}

extern "C" void kernel_launch(void* const* d_in, const int* in_sizes, int n_in,
                              void* d_out, int out_size, void* d_ws, size_t ws_size,
                              hipStream_t stream) {
  (void)n_in; (void)out_size;
  const float* x  = (const float*)d_in[0];
  const float* f0 = (const float*)d_in[1];
  float* out = (float*)d_out;
  // in_sizes[0] = B*T, in_sizes[1] = B*N with N = T/80 + 1  =>  B = in_sizes[1] - in_sizes[0]/80
  int B = in_sizes[1] - in_sizes[0] / 80;
  if (B < 1) B = 1;
  int Tlen = in_sizes[0] / B;
  int Nfr  = in_sizes[1] / B;

  float2* tw = nullptr;
  if (d_ws && ws_size >= 1538 * sizeof(float)) {
    tw = (float2*)d_ws;
    hipLaunchKernelGGL(init_tables, dim3(4), dim3(256), 0, stream, tw);
  }
  hipLaunchKernelGGL(cheaptrick_kernel, dim3(in_sizes[1]), dim3(256), 0, stream,
                     x, f0, out, Tlen, Nfr, (const float2*)tw);
}

// Round 9
// 174.493 us; speedup vs baseline: 1.2615x; 1.2203x over previous
//
#include <hip/hip_runtime.h>
#include <math.h>

#define PI_F 3.14159265358979323846f

// ---- 512-point complex Stockham radix-2 FFT in LDS, interleaved float2
// storage (b64 LDS ops), twiddles from TW table. TW[m] = (cos,sin)(pi*m/256).
// Result lands in Y (natural order). Enters and exits with __syncthreads().
__device__ __forceinline__ void fft512(float2* X, float2* Y, const float2* TW, int t) {
  float2* xr = X; float2* yr = Y;
#pragma unroll
  for (int s = 0; s < 9; ++s) {
    __syncthreads();
    const int m = 1 << s;
    float2 a = xr[t];
    float2 b = xr[t + 256];
    float2 w = TW[t & ~(m - 1)];              // e^{-i*pi*(t&~(m-1))/256}
    int o = t + (t & ~(m - 1));               // = k + 2*j*m
    float sr = a.x - b.x, si = a.y - b.y;
    yr[o] = make_float2(a.x + b.x, a.y + b.y);
    yr[o + m] = make_float2(sr * w.x + si * w.y, si * w.x - sr * w.y);
    float2* tp = xr; xr = yr; yr = tp;
  }
  __syncthreads();   // 9 stages (odd): result is in Y
}

// Real part of X[k] of the length-1024 real-input FFT whose packed 512-pt FFT
// is Z (natural order, float2). UP[k] = (cos,sin)(pi*k/512), k in [0,512].
__device__ __forceinline__ float unpack_re(const float2* Z, const float2* UP, int k) {
  int kk = k & 511, kr = (512 - k) & 511;
  float2 z = Z[kk], u = Z[kr];
  float Er = 0.5f * (z.x + u.x);
  float Or = 0.5f * (z.y + u.y), Oi = 0.5f * (u.x - z.x);
  float2 w = UP[k];
  return Er + w.x * Or + w.y * Oi;
}

__device__ __forceinline__ float unpack_pwr(const float2* Z, const float2* UP, int k) {
  int kk = k & 511, kr = (512 - k) & 511;
  float2 z = Z[kk], u = Z[kr];
  float Er = 0.5f * (z.x + u.x), Ei = 0.5f * (z.y - u.y);
  float Or = 0.5f * (z.y + u.y), Oi = 0.5f * (u.x - z.x);
  float2 w = UP[k];
  float re = Er + w.x * Or + w.y * Oi;
  float im = Ei + w.x * Oi - w.y * Or;
  return re * re + im * im;
}

// d_ws layout (as float2): [0,256) = TW (cos,sin)(pi*i/256); [256,769) = UP
// (cos,sin)(pi*k/512). 769 float2 = 6152 bytes.
__global__ __launch_bounds__(256) void init_tables(float2* __restrict__ w2) {
  int i = blockIdx.x * 256 + threadIdx.x;
  if (i < 256) {
    float sn, cs; sincosf((PI_F / 256.0f) * (float)i, &sn, &cs);
    w2[i] = make_float2(cs, sn);
  } else if (i < 769) {
    int k = i - 256;
    float sn, cs; sincosf((PI_F / 512.0f) * (float)k, &sn, &cs);
    w2[i] = make_float2(cs, sn);
  }
}

__global__ __launch_bounds__(256)
void cheaptrick_kernel(const float* __restrict__ x, const float* __restrict__ f0g,
                       float* __restrict__ out, int Tlen, int Nfr,
                       const float2* __restrict__ twg) {
  __shared__ float2 ZA[512], ZB[512];   // FFT ping-pong, interleaved complex
  __shared__ float2 ps2[257];           // aliased float ps[513] (8B-aligned pairs)
  __shared__ float C[642];              // prepended-zero cumsum
  __shared__ float red[16];
  __shared__ float2 TW[256];            // e^{-i pi m/256} (FFT twiddles)
  __shared__ float2 UP[513];            // e^{-i pi k/512} (real-FFT unpack)
  float* ps = (float*)ps2;

  const int t = threadIdx.x;
  const int blk = blockIdx.x;
  const int b = blk / Nfr;
  const int n = blk - b * Nfr;
  const int lane = t & 63, wave = t >> 6;
  const float RATE = 15.625f;

  // ---- load twiddle tables from ws (fallback computes in-kernel)
  if (twg) {
    TW[t] = twg[t];
    UP[t] = twg[256 + t];
    UP[t + 257] = twg[256 + t + 257];
    if (t == 0) UP[256] = twg[256 + 256];
  } else {
    float sn, cs;
    sincosf((PI_F / 256.0f) * (float)t, &sn, &cs);
    TW[t] = make_float2(cs, sn);
    sincosf((PI_F / 512.0f) * (float)t, &sn, &cs);
    UP[t] = make_float2(cs, sn);
    sincosf((PI_F / 512.0f) * (float)(t + 257), &sn, &cs);
    UP[t + 257] = make_float2(cs, sn);
    if (t == 0) UP[256] = make_float2(0.0f, 1.0f);
  }

  float f0v = f0g[blk];
  const float F_MIN = 3.0f * 16000.0f / 1021.0f;
  if (f0v <= F_MIN) f0v = 500.0f;

  // ---- windowed waveform: thread t owns samples {2t, 2t+1, 2t+512, 2t+513}
  float half_len = rintf(24000.0f / f0v);   // round-half-even matches jnp.round
  float wv[4], wd[4];
  float sw = 0.f, swin = 0.f;
  const int center = n * 80;
  const int ids[4] = {2 * t, 2 * t + 1, 2 * t + 512, 2 * t + 513};
#pragma unroll
  for (int q = 0; q < 4; ++q) {
    int base = ids[q] - 512;
    float fb = (float)base;
    float msk = (fabsf(fb) <= half_len) ? 1.0f : 0.0f;
    float win = (0.5f * __cosf(PI_F * (fb / 24000.0f) * f0v) + 0.5f) * msk;
    int src = center + base;
    src = min(max(src, 0), Tlen - 1);
    float wval = x[(size_t)b * (size_t)Tlen + src] * win;
    wd[q] = win; wv[q] = wval;
    sw += wval; swin += win;
  }
#pragma unroll
  for (int off = 32; off > 0; off >>= 1) {
    sw += __shfl_down(sw, off);
    swin += __shfl_down(swin, off);
  }
  if (lane == 0) { red[wave] = sw; red[4 + wave] = swin; }
  __syncthreads();
  float mf = (red[0] + red[1] + red[2] + red[3]) / (red[4] + red[5] + red[6] + red[7]);

  // pack z[m] = w[2m] + i*w[2m+1]
  ZA[t]       = make_float2(wv[0] - wd[0] * mf, wv[1] - wd[1] * mf);
  ZA[t + 256] = make_float2(wv[2] - wd[2] * mf, wv[3] - wd[3] * mf);

  fft512(ZA, ZB, TW, t);

  // ---- power spectrum |rfft|^2, k in [0,513)
  {
    float p0 = unpack_pwr(ZB, UP, t);
    float p1 = unpack_pwr(ZB, UP, t + 256);
    float p2 = (t == 0) ? unpack_pwr(ZB, UP, 512) : 0.f;
    ps[t] = p0; ps[t + 256] = p1;
    if (t == 0) ps[512] = p2;
  }
  __syncthreads();

  // ---- DC correction (only k < f0/RATE <= 32 matter)
  {
    float rep = 0.f;
    bool act = (t < 40);
    float kf = (float)t;
    if (act) {
      float pos = f0v / RATE - kf;
      int lo = (int)floorf(pos);
      lo = min(max(lo, 0), 511);
      float fr = pos - (float)lo;
      rep = ps[lo] * (1.0f - fr) + ps[lo + 1] * fr;
    }
    __syncthreads();
    if (act && kf * RATE < f0v) ps[t] += rep;
  }
  __syncthreads();

  // ---- linear smoothing: cumsum of mirrored extension (641 vals), then interp
  {
    const int ebase = 3 * t;
    float e0 = 0.f, e1 = 0.f, e2 = 0.f;
    {
      int e = ebase;
      if (e < 641)     { int j = e - 64;     j = j < 0 ? -j : j; if (j > 512) j = 1024 - j; e0 = ps[j]; }
      if (e + 1 < 641) { int j = e + 1 - 64; j = j < 0 ? -j : j; if (j > 512) j = 1024 - j; e1 = ps[j]; }
      if (e + 2 < 641) { int j = e + 2 - 64; j = j < 0 ? -j : j; if (j > 512) j = 1024 - j; e2 = ps[j]; }
    }
    float psum = e0 + e1 + e2;
    float sc = psum;
#pragma unroll
    for (int off = 1; off < 64; off <<= 1) {
      float v = __shfl_up(sc, off);
      if (lane >= off) sc += v;
    }
    if (lane == 63) red[8 + wave] = sc;
    __syncthreads();
    float woff = 0.f;
#pragma unroll
    for (int w2 = 0; w2 < 4; ++w2) woff += (w2 < wave) ? red[8 + w2] : 0.f;
    float run = woff + (sc - psum);    // exclusive prefix for this chunk
    if (t == 0) C[0] = 0.f;
    if (ebase < 641)     { run += e0; C[ebase + 1] = RATE * run; }
    if (ebase + 1 < 641) { run += e1; C[ebase + 2] = RATE * run; }
    if (ebase + 2 < 641) { run += e2; C[ebase + 3] = RATE * run; }
  }
  __syncthreads();

  // ---- interp smoothed spectrum, take log  (overwrite ps with lp)
  {
    const float width = f0v * (2.0f / 3.0f);
    const float hwb = width * (1.0f / (2.0f * RATE));
    const float winv = 1.0f / width;
    float s0, s1, s2 = 1.f;
#pragma unroll
    for (int r = 0; r < 3; ++r) {
      int k = (r == 0) ? t : (r == 1) ? (t + 256) : 512;
      if (r == 2 && t != 0) break;
      float kf = (float)k;
      float qh = kf + hwb + 64.5f, ql = kf - hwb + 64.5f;
      int lh = (int)floorf(qh); lh = min(max(lh, 0), 640);
      int ll = (int)floorf(ql); ll = min(max(ll, 0), 640);
      float fh = qh - (float)lh, fl = ql - (float)ll;
      float vh = C[lh] * (1.f - fh) + C[lh + 1] * fh;
      float vl = C[ll] * (1.f - fl) + C[ll + 1] * fl;
      float v = (vh - vl) * winv;
      if (r == 0) s0 = v; else if (r == 1) s1 = v; else s2 = v;
    }
    ps[t] = __logf(s0);
    ps[t + 256] = __logf(s1);
    if (t == 0) ps[512] = __logf(s2);
  }
  __syncthreads();

  // ---- cepstrum = irfft(lp): FFT of even extension, real part / 1024
  ZA[t] = ps2[t];   // (lp[2t], lp[2t+1]) as one b64
  {
    int idx1 = (2 * t + 512) <= 512 ? (2 * t + 512) : (1024 - (2 * t + 512));
    int idx2 = 1024 - (2 * t + 513);
    ZA[t + 256] = make_float2(ps[idx1], ps[idx2]);
  }
  fft512(ZA, ZB, TW, t);

  // ---- lifter, write lifted cepstrum into ps
  {
    const float inv = 1.0f / 1024.0f;
    float l0, l1, l2 = 0.f;
#pragma unroll
    for (int r = 0; r < 3; ++r) {
      int k = (r == 0) ? t : (r == 1) ? (t + 256) : 512;
      if (r == 2 && t != 0) break;
      float cep = unpack_re(ZB, UP, k) * inv;
      float z = f0v * ((float)k * (1.0f / 16000.0f));
      float pz = PI_F * z;
      float s = __sinf(pz);
      float sl = (k == 0) ? 1.0f : (s / pz);
      float cl = 1.0f + 0.6f * s * s;   // 1.3 - 0.3*cos(2pi z), cos(2a)=1-2sin^2(a)
      float v = cep * sl * cl;
      if (r == 0) l0 = v; else if (r == 1) l1 = v; else l2 = v;
    }
    ps[t] = l0; ps[t + 256] = l1;
    if (t == 0) ps[512] = l2;
  }
  __syncthreads();

  // ---- final hfft = 1024 * irfft(lifted): FFT of even extension, real part
  ZA[t] = ps2[t];
  {
    int idx1 = (2 * t + 512) <= 512 ? (2 * t + 512) : (1024 - (2 * t + 512));
    int idx2 = 1024 - (2 * t + 513);
    ZA[t + 256] = make_float2(ps[idx1], ps[idx2]);
  }
  fft512(ZA, ZB, TW, t);

  {
    size_t ob = (size_t)blk * 513;
    out[ob + t]       = unpack_re(ZB, UP, t);
    out[ob + t + 256] = unpack_re(ZB, UP, t + 256);
    if (t == 0) out[ob + 512] = unpack_re(ZB, UP, 512);
  }
}

extern "C" void kernel_launch(void* const* d_in, const int* in_sizes, int n_in,
                              void* d_out, int out_size, void* d_ws, size_t ws_size,
                              hipStream_t stream) {
  (void)n_in; (void)out_size;
  const float* x  = (const float*)d_in[0];
  const float* f0 = (const float*)d_in[1];
  float* out = (float*)d_out;
  // in_sizes[0] = B*T, in_sizes[1] = B*N with N = T/80 + 1  =>  B = in_sizes[1] - in_sizes[0]/80
  int B = in_sizes[1] - in_sizes[0] / 80;
  if (B < 1) B = 1;
  int Tlen = in_sizes[0] / B;
  int Nfr  = in_sizes[1] / B;

  float2* tw = nullptr;
  if (d_ws && ws_size >= 1538 * sizeof(float)) {
    tw = (float2*)d_ws;
    hipLaunchKernelGGL(init_tables, dim3(4), dim3(256), 0, stream, tw);
  }
  hipLaunchKernelGGL(cheaptrick_kernel, dim3(in_sizes[1]), dim3(256), 0, stream,
                     x, f0, out, Tlen, Nfr, (const float2*)tw);
}

// Round 10
// 156.551 us; speedup vs baseline: 1.4061x; 1.1146x over previous
//
#include <hip/hip_runtime.h>
#include <math.h>

#define PI_F 3.14159265358979323846f

// complex multiply by e^{-i theta} where w = (cos theta, sin theta)
__device__ __forceinline__ float2 cmuln(float2 a, float2 w) {
  return make_float2(a.x * w.x + a.y * w.y, a.y * w.x - a.x * w.y);
}

// ---- 512-pt mixed-radix Stockham FFT (DIT convention, natural order in/out).
// Stages: radix-4 at Ns=1,4,16,64 (threads 0..127, 4 pts/thread) then radix-2
// at Ns=256 (all 256 threads). Input in X, result lands in Y.
// TW[m] = (cos,sin)(pi*m/256) = e^{-2pi i m/512} (stored as +angle pair).
// Enters and exits with __syncthreads().
__device__ __forceinline__ void fft512(float2* X, float2* Y, const float2* TW, int t) {
  float2* xr = X; float2* yr = Y;
  // ---- stage Ns=1 (radix-4, no twiddles, contiguous float4 stores)
  __syncthreads();
  if (t < 128) {
    float2 a0 = xr[t], a1 = xr[t + 128], a2 = xr[t + 256], a3 = xr[t + 384];
    float T0x = a0.x + a2.x, T0y = a0.y + a2.y;
    float T1x = a0.x - a2.x, T1y = a0.y - a2.y;
    float T2x = a1.x + a3.x, T2y = a1.y + a3.y;
    float T3x = a1.x - a3.x, T3y = a1.y - a3.y;
    float4* y4 = (float4*)yr;
    y4[2 * t]     = make_float4(T0x + T2x, T0y + T2y, T1x + T3y, T1y - T3x);  // v0, v1
    y4[2 * t + 1] = make_float4(T0x - T2x, T0y - T2y, T1x - T3y, T1y + T3x);  // v2, v3
  }
  { float2* tp = xr; xr = yr; yr = tp; }
  // ---- stages Ns=4,16,64 (radix-4, twiddled)
#pragma unroll
  for (int ns = 4; ns <= 64; ns *= 4) {
    __syncthreads();
    if (t < 128) {
      float2 a0 = xr[t], a1 = xr[t + 128], a2 = xr[t + 256], a3 = xr[t + 384];
      int u = t & (ns - 1);
      int m1 = u * (128 / ns);
      float2 w1 = TW[m1], w2 = TW[2 * m1];
      // w3 = (cos,sin)(th1+th2)
      float2 w3 = make_float2(w1.x * w2.x - w1.y * w2.y, w1.y * w2.x + w1.x * w2.y);
      float2 b1 = cmuln(a1, w1);
      float2 b2 = cmuln(a2, w2);
      float2 b3 = cmuln(a3, w3);
      float T0x = a0.x + b2.x, T0y = a0.y + b2.y;
      float T1x = a0.x - b2.x, T1y = a0.y - b2.y;
      float T2x = b1.x + b3.x, T2y = b1.y + b3.y;
      float T3x = b1.x - b3.x, T3y = b1.y - b3.y;
      int idxD = (t / ns) * (4 * ns) + u;
      yr[idxD]          = make_float2(T0x + T2x, T0y + T2y);   // v0
      yr[idxD + ns]     = make_float2(T1x + T3y, T1y - T3x);   // v1 = T1 - i*T3
      yr[idxD + 2 * ns] = make_float2(T0x - T2x, T0y - T2y);   // v2
      yr[idxD + 3 * ns] = make_float2(T1x - T3y, T1y + T3x);   // v3 = T1 + i*T3
    }
    { float2* tp = xr; xr = yr; yr = tp; }
  }
  // ---- final radix-2 stage Ns=256 (all 256 threads)
  __syncthreads();
  {
    float2 a = xr[t], b = xr[t + 256];
    float2 bw = cmuln(b, TW[t]);          // e^{-2pi i t/512}
    yr[t]       = make_float2(a.x + bw.x, a.y + bw.y);
    yr[t + 256] = make_float2(a.x - bw.x, a.y - bw.y);
  }
  __syncthreads();   // result in original Y
}

// Real part of X[k] of the length-1024 real-input FFT whose packed 512-pt FFT
// is Z (natural order, float2). UP[k] = (cos,sin)(pi*k/512), k in [0,512].
__device__ __forceinline__ float unpack_re(const float2* Z, const float2* UP, int k) {
  int kk = k & 511, kr = (512 - k) & 511;
  float2 z = Z[kk], u = Z[kr];
  float Er = 0.5f * (z.x + u.x);
  float Or = 0.5f * (z.y + u.y), Oi = 0.5f * (u.x - z.x);
  float2 w = UP[k];
  return Er + w.x * Or + w.y * Oi;
}

__device__ __forceinline__ float unpack_pwr(const float2* Z, const float2* UP, int k) {
  int kk = k & 511, kr = (512 - k) & 511;
  float2 z = Z[kk], u = Z[kr];
  float Er = 0.5f * (z.x + u.x), Ei = 0.5f * (z.y - u.y);
  float Or = 0.5f * (z.y + u.y), Oi = 0.5f * (u.x - z.x);
  float2 w = UP[k];
  float re = Er + w.x * Or + w.y * Oi;
  float im = Ei + w.x * Oi - w.y * Or;
  return re * re + im * im;
}

// d_ws layout (as float2): [0,256) = TW (cos,sin)(pi*i/256); [256,769) = UP
// (cos,sin)(pi*k/512). 769 float2 = 6152 bytes.
__global__ __launch_bounds__(256) void init_tables(float2* __restrict__ w2) {
  int i = blockIdx.x * 256 + threadIdx.x;
  if (i < 256) {
    float sn, cs; sincosf((PI_F / 256.0f) * (float)i, &sn, &cs);
    w2[i] = make_float2(cs, sn);
  } else if (i < 769) {
    int k = i - 256;
    float sn, cs; sincosf((PI_F / 512.0f) * (float)k, &sn, &cs);
    w2[i] = make_float2(cs, sn);
  }
}

__global__ __launch_bounds__(256)
void cheaptrick_kernel(const float* __restrict__ x, const float* __restrict__ f0g,
                       float* __restrict__ out, int Tlen, int Nfr,
                       const float2* __restrict__ twg) {
  __shared__ __align__(16) float2 ZA[512], ZB[512];   // FFT ping-pong
  __shared__ float2 ps2[257];           // aliased float ps[513]
  __shared__ float C[642];              // prepended-zero cumsum
  __shared__ float red[16];
  __shared__ float2 TW[256];            // e^{-2pi i m/512} as (cos,sin)
  __shared__ float2 UP[513];            // e^{-i pi k/512} (real-FFT unpack)
  float* ps = (float*)ps2;

  const int t = threadIdx.x;
  const int blk = blockIdx.x;
  const int b = blk / Nfr;
  const int n = blk - b * Nfr;
  const int lane = t & 63, wave = t >> 6;
  const float RATE = 15.625f;

  // ---- load twiddle tables from ws (fallback computes in-kernel)
  if (twg) {
    TW[t] = twg[t];
    UP[t] = twg[256 + t];
    UP[t + 257] = twg[256 + t + 257];
    if (t == 0) UP[256] = twg[256 + 256];
  } else {
    float sn, cs;
    sincosf((PI_F / 256.0f) * (float)t, &sn, &cs);
    TW[t] = make_float2(cs, sn);
    sincosf((PI_F / 512.0f) * (float)t, &sn, &cs);
    UP[t] = make_float2(cs, sn);
    sincosf((PI_F / 512.0f) * (float)(t + 257), &sn, &cs);
    UP[t + 257] = make_float2(cs, sn);
    if (t == 0) UP[256] = make_float2(0.0f, 1.0f);
  }

  float f0v = f0g[blk];
  const float F_MIN = 3.0f * 16000.0f / 1021.0f;
  if (f0v <= F_MIN) f0v = 500.0f;

  // ---- windowed waveform: thread t owns samples {2t, 2t+1, 2t+512, 2t+513}
  float half_len = rintf(24000.0f / f0v);   // round-half-even matches jnp.round
  float wv[4], wd[4];
  float sw = 0.f, swin = 0.f;
  const int center = n * 80;
  const int ids[4] = {2 * t, 2 * t + 1, 2 * t + 512, 2 * t + 513};
#pragma unroll
  for (int q = 0; q < 4; ++q) {
    int base = ids[q] - 512;
    float fb = (float)base;
    float msk = (fabsf(fb) <= half_len) ? 1.0f : 0.0f;
    float win = (0.5f * __cosf(PI_F * (fb / 24000.0f) * f0v) + 0.5f) * msk;
    int src = center + base;
    src = min(max(src, 0), Tlen - 1);
    float wval = x[(size_t)b * (size_t)Tlen + src] * win;
    wd[q] = win; wv[q] = wval;
    sw += wval; swin += win;
  }
#pragma unroll
  for (int off = 32; off > 0; off >>= 1) {
    sw += __shfl_down(sw, off);
    swin += __shfl_down(swin, off);
  }
  if (lane == 0) { red[wave] = sw; red[4 + wave] = swin; }
  __syncthreads();
  float mf = (red[0] + red[1] + red[2] + red[3]) / (red[4] + red[5] + red[6] + red[7]);

  // pack z[m] = w[2m] + i*w[2m+1]
  ZA[t]       = make_float2(wv[0] - wd[0] * mf, wv[1] - wd[1] * mf);
  ZA[t + 256] = make_float2(wv[2] - wd[2] * mf, wv[3] - wd[3] * mf);

  fft512(ZA, ZB, TW, t);

  // ---- power spectrum |rfft|^2, k in [0,513)
  {
    float p0 = unpack_pwr(ZB, UP, t);
    float p1 = unpack_pwr(ZB, UP, t + 256);
    float p2 = (t == 0) ? unpack_pwr(ZB, UP, 512) : 0.f;
    ps[t] = p0; ps[t + 256] = p1;
    if (t == 0) ps[512] = p2;
  }
  __syncthreads();

  // ---- DC correction (only k < f0/RATE <= 32 matter)
  {
    float rep = 0.f;
    bool act = (t < 40);
    float kf = (float)t;
    if (act) {
      float pos = f0v / RATE - kf;
      int lo = (int)floorf(pos);
      lo = min(max(lo, 0), 511);
      float fr = pos - (float)lo;
      rep = ps[lo] * (1.0f - fr) + ps[lo + 1] * fr;
    }
    __syncthreads();
    if (act && kf * RATE < f0v) ps[t] += rep;
  }
  __syncthreads();

  // ---- linear smoothing: cumsum of mirrored extension (641 vals), then interp
  {
    const int ebase = 3 * t;
    float e0 = 0.f, e1 = 0.f, e2 = 0.f;
    {
      int e = ebase;
      if (e < 641)     { int j = e - 64;     j = j < 0 ? -j : j; if (j > 512) j = 1024 - j; e0 = ps[j]; }
      if (e + 1 < 641) { int j = e + 1 - 64; j = j < 0 ? -j : j; if (j > 512) j = 1024 - j; e1 = ps[j]; }
      if (e + 2 < 641) { int j = e + 2 - 64; j = j < 0 ? -j : j; if (j > 512) j = 1024 - j; e2 = ps[j]; }
    }
    float psum = e0 + e1 + e2;
    float sc = psum;
#pragma unroll
    for (int off = 1; off < 64; off <<= 1) {
      float v = __shfl_up(sc, off);
      if (lane >= off) sc += v;
    }
    if (lane == 63) red[8 + wave] = sc;
    __syncthreads();
    float woff = 0.f;
#pragma unroll
    for (int w2 = 0; w2 < 4; ++w2) woff += (w2 < wave) ? red[8 + w2] : 0.f;
    float run = woff + (sc - psum);    // exclusive prefix for this chunk
    if (t == 0) C[0] = 0.f;
    if (ebase < 641)     { run += e0; C[ebase + 1] = RATE * run; }
    if (ebase + 1 < 641) { run += e1; C[ebase + 2] = RATE * run; }
    if (ebase + 2 < 641) { run += e2; C[ebase + 3] = RATE * run; }
  }
  __syncthreads();

  // ---- interp smoothed spectrum, take log  (overwrite ps with lp)
  {
    const float width = f0v * (2.0f / 3.0f);
    const float hwb = width * (1.0f / (2.0f * RATE));
    const float winv = 1.0f / width;
    float s0, s1, s2 = 1.f;
#pragma unroll
    for (int r = 0; r < 3; ++r) {
      int k = (r == 0) ? t : (r == 1) ? (t + 256) : 512;
      if (r == 2 && t != 0) break;
      float kf = (float)k;
      float qh = kf + hwb + 64.5f, ql = kf - hwb + 64.5f;
      int lh = (int)floorf(qh); lh = min(max(lh, 0), 640);
      int ll = (int)floorf(ql); ll = min(max(ll, 0), 640);
      float fh = qh - (float)lh, fl = ql - (float)ll;
      float vh = C[lh] * (1.f - fh) + C[lh + 1] * fh;
      float vl = C[ll] * (1.f - fl) + C[ll + 1] * fl;
      float v = (vh - vl) * winv;
      if (r == 0) s0 = v; else if (r == 1) s1 = v; else s2 = v;
    }
    ps[t] = __logf(s0);
    ps[t + 256] = __logf(s1);
    if (t == 0) ps[512] = __logf(s2);
  }
  __syncthreads();

  // ---- cepstrum = irfft(lp): FFT of even extension, real part / 1024
  ZA[t] = ps2[t];   // (lp[2t], lp[2t+1]) as one b64
  {
    int idx1 = (2 * t + 512) <= 512 ? (2 * t + 512) : (1024 - (2 * t + 512));
    int idx2 = 1024 - (2 * t + 513);
    ZA[t + 256] = make_float2(ps[idx1], ps[idx2]);
  }
  fft512(ZA, ZB, TW, t);

  // ---- lifter, write lifted cepstrum into ps
  {
    const float inv = 1.0f / 1024.0f;
    float l0, l1, l2 = 0.f;
#pragma unroll
    for (int r = 0; r < 3; ++r) {
      int k = (r == 0) ? t : (r == 1) ? (t + 256) : 512;
      if (r == 2 && t != 0) break;
      float cep = unpack_re(ZB, UP, k) * inv;
      float z = f0v * ((float)k * (1.0f / 16000.0f));
      float pz = PI_F * z;
      float s = __sinf(pz);
      float sl = (k == 0) ? 1.0f : (s / pz);
      float cl = 1.0f + 0.6f * s * s;   // 1.3 - 0.3*cos(2pi z), cos(2a)=1-2sin^2(a)
      float v = cep * sl * cl;
      if (r == 0) l0 = v; else if (r == 1) l1 = v; else l2 = v;
    }
    ps[t] = l0; ps[t + 256] = l1;
    if (t == 0) ps[512] = l2;
  }
  __syncthreads();

  // ---- final hfft = 1024 * irfft(lifted): FFT of even extension, real part
  ZA[t] = ps2[t];
  {
    int idx1 = (2 * t + 512) <= 512 ? (2 * t + 512) : (1024 - (2 * t + 512));
    int idx2 = 1024 - (2 * t + 513);
    ZA[t + 256] = make_float2(ps[idx1], ps[idx2]);
  }
  fft512(ZA, ZB, TW, t);

  {
    size_t ob = (size_t)blk * 513;
    out[ob + t]       = unpack_re(ZB, UP, t);
    out[ob + t + 256] = unpack_re(ZB, UP, t + 256);
    if (t == 0) out[ob + 512] = unpack_re(ZB, UP, 512);
  }
}

extern "C" void kernel_launch(void* const* d_in, const int* in_sizes, int n_in,
                              void* d_out, int out_size, void* d_ws, size_t ws_size,
                              hipStream_t stream) {
  (void)n_in; (void)out_size;
  const float* x  = (const float*)d_in[0];
  const float* f0 = (const float*)d_in[1];
  float* out = (float*)d_out;
  // in_sizes[0] = B*T, in_sizes[1] = B*N with N = T/80 + 1  =>  B = in_sizes[1] - in_sizes[0]/80
  int B = in_sizes[1] - in_sizes[0] / 80;
  if (B < 1) B = 1;
  int Tlen = in_sizes[0] / B;
  int Nfr  = in_sizes[1] / B;

  float2* tw = nullptr;
  if (d_ws && ws_size >= 1538 * sizeof(float)) {
    tw = (float2*)d_ws;
    hipLaunchKernelGGL(init_tables, dim3(4), dim3(256), 0, stream, tw);
  }
  hipLaunchKernelGGL(cheaptrick_kernel, dim3(in_sizes[1]), dim3(256), 0, stream,
                     x, f0, out, Tlen, Nfr, (const float2*)tw);
}

// Round 11
// 156.280 us; speedup vs baseline: 1.4085x; 1.0017x over previous
//
#include <hip/hip_runtime.h>
#include <math.h>

#define PI_F 3.14159265358979323846f

// complex multiply by e^{-i theta} where w = (cos theta, sin theta)
__device__ __forceinline__ float2 cmuln(float2 a, float2 w) {
  return make_float2(a.x * w.x + a.y * w.y, a.y * w.x - a.x * w.y);
}

// Involution swizzle for the 16-way-conflicted generations (Ns=1/Ns=4 writes):
// bits[3:2] ^= bits[5:4], bits[1:0] ^= bits[7:6]. Bijective on [0,512);
// contiguous reads stay 2-way, strided quad-writes drop 16-way -> 4-way.
__device__ __forceinline__ int S1(int i) {
  return i ^ (((i >> 4) & 3) << 2) ^ ((i >> 6) & 3);
}

// ---- 512-pt mixed-radix Stockham FFT (natural order in/out).
// Stages: radix-4 at Ns=1,4,16,64 (threads 0..127) then radix-2 at Ns=256.
// Generations written by Ns=1 and Ns=4 stages use the S1 LDS swizzle.
// TW[m] = (cos,sin)(pi*m/256) = e^{-2pi i m/512}. Enters/exits with barrier.
__device__ __forceinline__ void fft512(float2* X, float2* Y, const float2* TW, int t) {
  float2* xr = X; float2* yr = Y;
  // ---- stage Ns=1 (radix-4, no twiddles) -> writes swizzled (gen1)
  __syncthreads();
  if (t < 128) {
    float2 a0 = xr[t], a1 = xr[t + 128], a2 = xr[t + 256], a3 = xr[t + 384];
    float T0x = a0.x + a2.x, T0y = a0.y + a2.y;
    float T1x = a0.x - a2.x, T1y = a0.y - a2.y;
    float T2x = a1.x + a3.x, T2y = a1.y + a3.y;
    float T3x = a1.x - a3.x, T3y = a1.y - a3.y;
    int o = 4 * t;
    yr[S1(o)]     = make_float2(T0x + T2x, T0y + T2y);   // v0
    yr[S1(o + 1)] = make_float2(T1x + T3y, T1y - T3x);   // v1
    yr[S1(o + 2)] = make_float2(T0x - T2x, T0y - T2y);   // v2
    yr[S1(o + 3)] = make_float2(T1x - T3y, T1y + T3x);   // v3
  }
  { float2* tp = xr; xr = yr; yr = tp; }
  // ---- stage Ns=4 (radix-4): reads swizzled (gen1), writes swizzled (gen2)
  __syncthreads();
  if (t < 128) {
    float2 a0 = xr[S1(t)], a1 = xr[S1(t + 128)], a2 = xr[S1(t + 256)], a3 = xr[S1(t + 384)];
    int u = t & 3;
    int m1 = u * 32;
    float2 w1 = TW[m1], w2 = TW[2 * m1];
    float2 w3 = make_float2(w1.x * w2.x - w1.y * w2.y, w1.y * w2.x + w1.x * w2.y);
    float2 b1 = cmuln(a1, w1);
    float2 b2 = cmuln(a2, w2);
    float2 b3 = cmuln(a3, w3);
    float T0x = a0.x + b2.x, T0y = a0.y + b2.y;
    float T1x = a0.x - b2.x, T1y = a0.y - b2.y;
    float T2x = b1.x + b3.x, T2y = b1.y + b3.y;
    float T3x = b1.x - b3.x, T3y = b1.y - b3.y;
    int idxD = (t >> 2) * 16 + u;
    yr[S1(idxD)]      = make_float2(T0x + T2x, T0y + T2y);
    yr[S1(idxD + 4)]  = make_float2(T1x + T3y, T1y - T3x);
    yr[S1(idxD + 8)]  = make_float2(T0x - T2x, T0y - T2y);
    yr[S1(idxD + 12)] = make_float2(T1x - T3y, T1y + T3x);
  }
  { float2* tp = xr; xr = yr; yr = tp; }
  // ---- stage Ns=16 (radix-4): reads swizzled (gen2), writes identity (gen3, 4-way)
  __syncthreads();
  if (t < 128) {
    float2 a0 = xr[S1(t)], a1 = xr[S1(t + 128)], a2 = xr[S1(t + 256)], a3 = xr[S1(t + 384)];
    int u = t & 15;
    int m1 = u * 8;
    float2 w1 = TW[m1], w2 = TW[2 * m1];
    float2 w3 = make_float2(w1.x * w2.x - w1.y * w2.y, w1.y * w2.x + w1.x * w2.y);
    float2 b1 = cmuln(a1, w1);
    float2 b2 = cmuln(a2, w2);
    float2 b3 = cmuln(a3, w3);
    float T0x = a0.x + b2.x, T0y = a0.y + b2.y;
    float T1x = a0.x - b2.x, T1y = a0.y - b2.y;
    float T2x = b1.x + b3.x, T2y = b1.y + b3.y;
    float T3x = b1.x - b3.x, T3y = b1.y - b3.y;
    int idxD = (t >> 4) * 64 + u;
    yr[idxD]      = make_float2(T0x + T2x, T0y + T2y);
    yr[idxD + 16] = make_float2(T1x + T3y, T1y - T3x);
    yr[idxD + 32] = make_float2(T0x - T2x, T0y - T2y);
    yr[idxD + 48] = make_float2(T1x - T3y, T1y + T3x);
  }
  { float2* tp = xr; xr = yr; yr = tp; }
  // ---- stage Ns=64 (radix-4): identity both sides (reads contig, writes 2-way)
  __syncthreads();
  if (t < 128) {
    float2 a0 = xr[t], a1 = xr[t + 128], a2 = xr[t + 256], a3 = xr[t + 384];
    int u = t & 63;
    int m1 = u * 2;
    float2 w1 = TW[m1], w2 = TW[2 * m1];
    float2 w3 = make_float2(w1.x * w2.x - w1.y * w2.y, w1.y * w2.x + w1.x * w2.y);
    float2 b1 = cmuln(a1, w1);
    float2 b2 = cmuln(a2, w2);
    float2 b3 = cmuln(a3, w3);
    float T0x = a0.x + b2.x, T0y = a0.y + b2.y;
    float T1x = a0.x - b2.x, T1y = a0.y - b2.y;
    float T2x = b1.x + b3.x, T2y = b1.y + b3.y;
    float T3x = b1.x - b3.x, T3y = b1.y - b3.y;
    int idxD = (t >> 6) * 256 + u;
    yr[idxD]       = make_float2(T0x + T2x, T0y + T2y);
    yr[idxD + 64]  = make_float2(T1x + T3y, T1y - T3x);
    yr[idxD + 128] = make_float2(T0x - T2x, T0y - T2y);
    yr[idxD + 192] = make_float2(T1x - T3y, T1y + T3x);
  }
  { float2* tp = xr; xr = yr; yr = tp; }
  // ---- final radix-2 stage Ns=256 (all 256 threads), identity
  __syncthreads();
  {
    float2 a = xr[t], b = xr[t + 256];
    float2 bw = cmuln(b, TW[t]);          // e^{-2pi i t/512}
    yr[t]       = make_float2(a.x + bw.x, a.y + bw.y);
    yr[t + 256] = make_float2(a.x - bw.x, a.y - bw.y);
  }
  __syncthreads();   // result in original Y (5 stages: X->Y->X->Y->X->Y)
}

// Real part of X[k] of the length-1024 real-input FFT whose packed 512-pt FFT
// is Z (natural order, float2). UP[k] = (cos,sin)(pi*k/512), k in [0,512].
__device__ __forceinline__ float unpack_re(const float2* Z, const float2* UP, int k) {
  int kk = k & 511, kr = (512 - k) & 511;
  float2 z = Z[kk], u = Z[kr];
  float Er = 0.5f * (z.x + u.x);
  float Or = 0.5f * (z.y + u.y), Oi = 0.5f * (u.x - z.x);
  float2 w = UP[k];
  return Er + w.x * Or + w.y * Oi;
}

__device__ __forceinline__ float unpack_pwr(const float2* Z, const float2* UP, int k) {
  int kk = k & 511, kr = (512 - k) & 511;
  float2 z = Z[kk], u = Z[kr];
  float Er = 0.5f * (z.x + u.x), Ei = 0.5f * (z.y - u.y);
  float Or = 0.5f * (z.y + u.y), Oi = 0.5f * (u.x - z.x);
  float2 w = UP[k];
  float re = Er + w.x * Or + w.y * Oi;
  float im = Ei + w.x * Oi - w.y * Or;
  return re * re + im * im;
}

// d_ws layout (as float2): [0,256) = TW (cos,sin)(pi*i/256); [256,769) = UP
// (cos,sin)(pi*k/512). 769 float2 = 6152 bytes.
__global__ __launch_bounds__(256) void init_tables(float2* __restrict__ w2) {
  int i = blockIdx.x * 256 + threadIdx.x;
  if (i < 256) {
    float sn, cs; sincosf((PI_F / 256.0f) * (float)i, &sn, &cs);
    w2[i] = make_float2(cs, sn);
  } else if (i < 769) {
    int k = i - 256;
    float sn, cs; sincosf((PI_F / 512.0f) * (float)k, &sn, &cs);
    w2[i] = make_float2(cs, sn);
  }
}

__global__ __launch_bounds__(256)
void cheaptrick_kernel(const float* __restrict__ x, const float* __restrict__ f0g,
                       float* __restrict__ out, int Tlen, int Nfr,
                       const float2* __restrict__ twg) {
  __shared__ __align__(16) float2 ZA[512], ZB[512];   // FFT ping-pong
  __shared__ float2 ps2[257];           // aliased float ps[513]
  __shared__ float C[642];              // prepended-zero cumsum
  __shared__ float red[16];
  __shared__ float2 TW[256];            // e^{-2pi i m/512} as (cos,sin)
  __shared__ float2 UP[513];            // e^{-i pi k/512} (real-FFT unpack)
  float* ps = (float*)ps2;

  const int t = threadIdx.x;
  const int blk = blockIdx.x;
  const int b = blk / Nfr;
  const int n = blk - b * Nfr;
  const int lane = t & 63, wave = t >> 6;
  const float RATE = 15.625f;

  // ---- load twiddle tables from ws (fallback computes in-kernel)
  if (twg) {
    TW[t] = twg[t];
    UP[t] = twg[256 + t];
    UP[t + 257] = twg[256 + t + 257];
    if (t == 0) UP[256] = twg[256 + 256];
  } else {
    float sn, cs;
    sincosf((PI_F / 256.0f) * (float)t, &sn, &cs);
    TW[t] = make_float2(cs, sn);
    sincosf((PI_F / 512.0f) * (float)t, &sn, &cs);
    UP[t] = make_float2(cs, sn);
    sincosf((PI_F / 512.0f) * (float)(t + 257), &sn, &cs);
    UP[t + 257] = make_float2(cs, sn);
    if (t == 0) UP[256] = make_float2(0.0f, 1.0f);
  }

  float f0v = f0g[blk];
  const float F_MIN = 3.0f * 16000.0f / 1021.0f;
  if (f0v <= F_MIN) f0v = 500.0f;

  // ---- windowed waveform: thread t owns samples {2t, 2t+1, 2t+512, 2t+513}
  float half_len = rintf(24000.0f / f0v);   // round-half-even matches jnp.round
  float wv[4], wd[4];
  float sw = 0.f, swin = 0.f;
  const int center = n * 80;
  const int ids[4] = {2 * t, 2 * t + 1, 2 * t + 512, 2 * t + 513};
#pragma unroll
  for (int q = 0; q < 4; ++q) {
    int base = ids[q] - 512;
    float fb = (float)base;
    float msk = (fabsf(fb) <= half_len) ? 1.0f : 0.0f;
    float win = (0.5f * __cosf(PI_F * (fb / 24000.0f) * f0v) + 0.5f) * msk;
    int src = center + base;
    src = min(max(src, 0), Tlen - 1);
    float wval = x[(size_t)b * (size_t)Tlen + src] * win;
    wd[q] = win; wv[q] = wval;
    sw += wval; swin += win;
  }
#pragma unroll
  for (int off = 32; off > 0; off >>= 1) {
    sw += __shfl_down(sw, off);
    swin += __shfl_down(swin, off);
  }
  if (lane == 0) { red[wave] = sw; red[4 + wave] = swin; }
  __syncthreads();
  float mf = (red[0] + red[1] + red[2] + red[3]) / (red[4] + red[5] + red[6] + red[7]);

  // pack z[m] = w[2m] + i*w[2m+1]
  ZA[t]       = make_float2(wv[0] - wd[0] * mf, wv[1] - wd[1] * mf);
  ZA[t + 256] = make_float2(wv[2] - wd[2] * mf, wv[3] - wd[3] * mf);

  fft512(ZA, ZB, TW, t);

  // ---- power spectrum |rfft|^2, k in [0,513)
  {
    float p0 = unpack_pwr(ZB, UP, t);
    float p1 = unpack_pwr(ZB, UP, t + 256);
    float p2 = (t == 0) ? unpack_pwr(ZB, UP, 512) : 0.f;
    ps[t] = p0; ps[t + 256] = p1;
    if (t == 0) ps[512] = p2;
  }
  __syncthreads();

  // ---- DC correction (only k < f0/RATE <= 32 matter)
  {
    float rep = 0.f;
    bool act = (t < 40);
    float kf = (float)t;
    if (act) {
      float pos = f0v / RATE - kf;
      int lo = (int)floorf(pos);
      lo = min(max(lo, 0), 511);
      float fr = pos - (float)lo;
      rep = ps[lo] * (1.0f - fr) + ps[lo + 1] * fr;
    }
    __syncthreads();
    if (act && kf * RATE < f0v) ps[t] += rep;
  }
  __syncthreads();

  // ---- linear smoothing: cumsum of mirrored extension (641 vals), then interp
  {
    const int ebase = 3 * t;
    float e0 = 0.f, e1 = 0.f, e2 = 0.f;
    {
      int e = ebase;
      if (e < 641)     { int j = e - 64;     j = j < 0 ? -j : j; if (j > 512) j = 1024 - j; e0 = ps[j]; }
      if (e + 1 < 641) { int j = e + 1 - 64; j = j < 0 ? -j : j; if (j > 512) j = 1024 - j; e1 = ps[j]; }
      if (e + 2 < 641) { int j = e + 2 - 64; j = j < 0 ? -j : j; if (j > 512) j = 1024 - j; e2 = ps[j]; }
    }
    float psum = e0 + e1 + e2;
    float sc = psum;
#pragma unroll
    for (int off = 1; off < 64; off <<= 1) {
      float v = __shfl_up(sc, off);
      if (lane >= off) sc += v;
    }
    if (lane == 63) red[8 + wave] = sc;
    __syncthreads();
    float woff = 0.f;
#pragma unroll
    for (int w2 = 0; w2 < 4; ++w2) woff += (w2 < wave) ? red[8 + w2] : 0.f;
    float run = woff + (sc - psum);    // exclusive prefix for this chunk
    if (t == 0) C[0] = 0.f;
    if (ebase < 641)     { run += e0; C[ebase + 1] = RATE * run; }
    if (ebase + 1 < 641) { run += e1; C[ebase + 2] = RATE * run; }
    if (ebase + 2 < 641) { run += e2; C[ebase + 3] = RATE * run; }
  }
  __syncthreads();

  // ---- interp smoothed spectrum, take log  (overwrite ps with lp)
  {
    const float width = f0v * (2.0f / 3.0f);
    const float hwb = width * (1.0f / (2.0f * RATE));
    const float winv = 1.0f / width;
    float s0, s1, s2 = 1.f;
#pragma unroll
    for (int r = 0; r < 3; ++r) {
      int k = (r == 0) ? t : (r == 1) ? (t + 256) : 512;
      if (r == 2 && t != 0) break;
      float kf = (float)k;
      float qh = kf + hwb + 64.5f, ql = kf - hwb + 64.5f;
      int lh = (int)floorf(qh); lh = min(max(lh, 0), 640);
      int ll = (int)floorf(ql); ll = min(max(ll, 0), 640);
      float fh = qh - (float)lh, fl = ql - (float)ll;
      float vh = C[lh] * (1.f - fh) + C[lh + 1] * fh;
      float vl = C[ll] * (1.f - fl) + C[ll + 1] * fl;
      float v = (vh - vl) * winv;
      if (r == 0) s0 = v; else if (r == 1) s1 = v; else s2 = v;
    }
    ps[t] = __logf(s0);
    ps[t + 256] = __logf(s1);
    if (t == 0) ps[512] = __logf(s2);
  }
  __syncthreads();

  // ---- cepstrum = irfft(lp): FFT of even extension, real part / 1024
  ZA[t] = ps2[t];   // (lp[2t], lp[2t+1]) as one b64
  {
    int idx1 = (2 * t + 512) <= 512 ? (2 * t + 512) : (1024 - (2 * t + 512));
    int idx2 = 1024 - (2 * t + 513);
    ZA[t + 256] = make_float2(ps[idx1], ps[idx2]);
  }
  fft512(ZA, ZB, TW, t);

  // ---- lifter, write lifted cepstrum into ps
  {
    const float inv = 1.0f / 1024.0f;
    float l0, l1, l2 = 0.f;
#pragma unroll
    for (int r = 0; r < 3; ++r) {
      int k = (r == 0) ? t : (r == 1) ? (t + 256) : 512;
      if (r == 2 && t != 0) break;
      float cep = unpack_re(ZB, UP, k) * inv;
      float z = f0v * ((float)k * (1.0f / 16000.0f));
      float pz = PI_F * z;
      float s = __sinf(pz);
      float sl = (k == 0) ? 1.0f : (s / pz);
      float cl = 1.0f + 0.6f * s * s;   // 1.3 - 0.3*cos(2pi z), cos(2a)=1-2sin^2(a)
      float v = cep * sl * cl;
      if (r == 0) l0 = v; else if (r == 1) l1 = v; else l2 = v;
    }
    ps[t] = l0; ps[t + 256] = l1;
    if (t == 0) ps[512] = l2;
  }
  __syncthreads();

  // ---- final hfft = 1024 * irfft(lifted): FFT of even extension, real part
  ZA[t] = ps2[t];
  {
    int idx1 = (2 * t + 512) <= 512 ? (2 * t + 512) : (1024 - (2 * t + 512));
    int idx2 = 1024 - (2 * t + 513);
    ZA[t + 256] = make_float2(ps[idx1], ps[idx2]);
  }
  fft512(ZA, ZB, TW, t);

  {
    size_t ob = (size_t)blk * 513;
    out[ob + t]       = unpack_re(ZB, UP, t);
    out[ob + t + 256] = unpack_re(ZB, UP, t + 256);
    if (t == 0) out[ob + 512] = unpack_re(ZB, UP, 512);
  }
}

extern "C" void kernel_launch(void* const* d_in, const int* in_sizes, int n_in,
                              void* d_out, int out_size, void* d_ws, size_t ws_size,
                              hipStream_t stream) {
  (void)n_in; (void)out_size;
  const float* x  = (const float*)d_in[0];
  const float* f0 = (const float*)d_in[1];
  float* out = (float*)d_out;
  // in_sizes[0] = B*T, in_sizes[1] = B*N with N = T/80 + 1  =>  B = in_sizes[1] - in_sizes[0]/80
  int B = in_sizes[1] - in_sizes[0] / 80;
  if (B < 1) B = 1;
  int Tlen = in_sizes[0] / B;
  int Nfr  = in_sizes[1] / B;

  float2* tw = nullptr;
  if (d_ws && ws_size >= 1538 * sizeof(float)) {
    tw = (float2*)d_ws;
    hipLaunchKernelGGL(init_tables, dim3(4), dim3(256), 0, stream, tw);
  }
  hipLaunchKernelGGL(cheaptrick_kernel, dim3(in_sizes[1]), dim3(256), 0, stream,
                     x, f0, out, Tlen, Nfr, (const float2*)tw);
}

// Round 12
// 152.397 us; speedup vs baseline: 1.4444x; 1.0255x over previous
//
#include <hip/hip_runtime.h>
#include <math.h>

#define PI_F 3.14159265358979323846f

// complex multiply by e^{-i theta} where w = (cos theta, sin theta)
__device__ __forceinline__ float2 cmuln(float2 a, float2 w) {
  return make_float2(a.x * w.x + a.y * w.y, a.y * w.x - a.x * w.y);
}

// ---- 512-pt mixed-radix Stockham FFT (natural order in/out).  [R10 exact]
// Stages: radix-4 at Ns=1,4,16,64 (threads 0..127) then radix-2 at Ns=256.
// TW[m] = (cos,sin)(pi*m/256) = e^{-2pi i m/512}. Enters/exits with barrier.
__device__ __forceinline__ void fft512(float2* X, float2* Y, const float2* TW, int t) {
  float2* xr = X; float2* yr = Y;
  // ---- stage Ns=1 (radix-4, no twiddles, contiguous float4 stores)
  __syncthreads();
  if (t < 128) {
    float2 a0 = xr[t], a1 = xr[t + 128], a2 = xr[t + 256], a3 = xr[t + 384];
    float T0x = a0.x + a2.x, T0y = a0.y + a2.y;
    float T1x = a0.x - a2.x, T1y = a0.y - a2.y;
    float T2x = a1.x + a3.x, T2y = a1.y + a3.y;
    float T3x = a1.x - a3.x, T3y = a1.y - a3.y;
    float4* y4 = (float4*)yr;
    y4[2 * t]     = make_float4(T0x + T2x, T0y + T2y, T1x + T3y, T1y - T3x);  // v0, v1
    y4[2 * t + 1] = make_float4(T0x - T2x, T0y - T2y, T1x - T3y, T1y + T3x);  // v2, v3
  }
  { float2* tp = xr; xr = yr; yr = tp; }
  // ---- stages Ns=4,16,64 (radix-4, twiddled)
#pragma unroll
  for (int ns = 4; ns <= 64; ns *= 4) {
    __syncthreads();
    if (t < 128) {
      float2 a0 = xr[t], a1 = xr[t + 128], a2 = xr[t + 256], a3 = xr[t + 384];
      int u = t & (ns - 1);
      int m1 = u * (128 / ns);
      float2 w1 = TW[m1], w2 = TW[2 * m1];
      float2 w3 = make_float2(w1.x * w2.x - w1.y * w2.y, w1.y * w2.x + w1.x * w2.y);
      float2 b1 = cmuln(a1, w1);
      float2 b2 = cmuln(a2, w2);
      float2 b3 = cmuln(a3, w3);
      float T0x = a0.x + b2.x, T0y = a0.y + b2.y;
      float T1x = a0.x - b2.x, T1y = a0.y - b2.y;
      float T2x = b1.x + b3.x, T2y = b1.y + b3.y;
      float T3x = b1.x - b3.x, T3y = b1.y - b3.y;
      int idxD = (t / ns) * (4 * ns) + u;
      yr[idxD]          = make_float2(T0x + T2x, T0y + T2y);   // v0
      yr[idxD + ns]     = make_float2(T1x + T3y, T1y - T3x);   // v1
      yr[idxD + 2 * ns] = make_float2(T0x - T2x, T0y - T2y);   // v2
      yr[idxD + 3 * ns] = make_float2(T1x - T3y, T1y + T3x);   // v3
    }
    { float2* tp = xr; xr = yr; yr = tp; }
  }
  // ---- final radix-2 stage Ns=256 (all 256 threads)
  __syncthreads();
  {
    float2 a = xr[t], b = xr[t + 256];
    float2 bw = cmuln(b, TW[t]);          // e^{-2pi i t/512}
    yr[t]       = make_float2(a.x + bw.x, a.y + bw.y);
    yr[t + 256] = make_float2(a.x - bw.x, a.y - bw.y);
  }
  __syncthreads();   // result in original Y
}

// lifter factor: sinc(f0 k/16000) * (1.3 - 0.3 cos(2 pi f0 k/16000))
__device__ __forceinline__ float lift_f(float f0v, int k) {
  float z = f0v * ((float)k * (1.0f / 16000.0f));
  float pz = PI_F * z;
  float s = __sinf(pz);
  float sl = (k == 0) ? 1.0f : (s / pz);
  return sl * (1.0f + 0.6f * s * s);
}

// d_ws layout (as float2): [0,256) = TW (cos,sin)(pi*i/256); [256,769) = UP
// (cos,sin)(pi*k/512). 769 float2 = 6152 bytes.
__global__ __launch_bounds__(256) void init_tables(float2* __restrict__ w2) {
  int i = blockIdx.x * 256 + threadIdx.x;
  if (i < 256) {
    float sn, cs; sincosf((PI_F / 256.0f) * (float)i, &sn, &cs);
    w2[i] = make_float2(cs, sn);
  } else if (i < 769) {
    int k = i - 256;
    float sn, cs; sincosf((PI_F / 512.0f) * (float)k, &sn, &cs);
    w2[i] = make_float2(cs, sn);
  }
}

__global__ __launch_bounds__(256)
void cheaptrick_kernel(const float* __restrict__ x, const float* __restrict__ f0g,
                       float* __restrict__ out, int Tlen, int Nfr,
                       const float2* __restrict__ twg) {
  __shared__ __align__(16) float2 ZA[512], ZB[512];   // FFT ping-pong
  __shared__ float2 ps2[257];           // aliased float ps[513]
  __shared__ float C[642];              // prepended-zero cumsum
  __shared__ float red[16];
  __shared__ float2 TW[256];            // e^{-2pi i m/512} as (cos,sin)
  __shared__ float2 UP[256];            // e^{-i pi k/512}, k in [0,256)
  float* ps = (float*)ps2;

  const int t = threadIdx.x;
  const int blk = blockIdx.x;
  const int b = blk / Nfr;
  const int n = blk - b * Nfr;
  const int lane = t & 63, wave = t >> 6;
  const float RATE = 15.625f;

  // ---- load twiddle tables from ws (fallback computes in-kernel)
  if (twg) {
    TW[t] = twg[t];
    UP[t] = twg[256 + t];
  } else {
    float sn, cs;
    sincosf((PI_F / 256.0f) * (float)t, &sn, &cs);
    TW[t] = make_float2(cs, sn);
    sincosf((PI_F / 512.0f) * (float)t, &sn, &cs);
    UP[t] = make_float2(cs, sn);
  }

  float f0v = f0g[blk];
  const float F_MIN = 3.0f * 16000.0f / 1021.0f;
  if (f0v <= F_MIN) f0v = 500.0f;

  // ---- windowed waveform: thread t owns samples {2t, 2t+1, 2t+512, 2t+513}
  float half_len = rintf(24000.0f / f0v);   // round-half-even matches jnp.round
  float wv[4], wd[4];
  float sw = 0.f, swin = 0.f;
  const int center = n * 80;
  const int ids[4] = {2 * t, 2 * t + 1, 2 * t + 512, 2 * t + 513};
#pragma unroll
  for (int q = 0; q < 4; ++q) {
    int base = ids[q] - 512;
    float fb = (float)base;
    float msk = (fabsf(fb) <= half_len) ? 1.0f : 0.0f;
    float win = (0.5f * __cosf(PI_F * (fb / 24000.0f) * f0v) + 0.5f) * msk;
    int src = center + base;
    src = min(max(src, 0), Tlen - 1);
    float wval = x[(size_t)b * (size_t)Tlen + src] * win;
    wd[q] = win; wv[q] = wval;
    sw += wval; swin += win;
  }
#pragma unroll
  for (int off = 32; off > 0; off >>= 1) {
    sw += __shfl_down(sw, off);
    swin += __shfl_down(swin, off);
  }
  if (lane == 0) { red[wave] = sw; red[4 + wave] = swin; }
  __syncthreads();
  float mf = (red[0] + red[1] + red[2] + red[3]) / (red[4] + red[5] + red[6] + red[7]);

  // pack z[m] = w[2m] + i*w[2m+1]
  ZA[t]       = make_float2(wv[0] - wd[0] * mf, wv[1] - wd[1] * mf);
  ZA[t + 256] = make_float2(wv[2] - wd[2] * mf, wv[3] - wd[3] * mf);

  fft512(ZA, ZB, TW, t);

  // ---- power spectrum |rfft|^2: paired unpack (k, 512-k) per thread
  if (t == 0) {
    float2 z0 = ZB[0];
    float s = z0.x + z0.y, d = z0.x - z0.y;
    float2 zq = ZB[256];
    ps[0] = s * s;
    ps[512] = d * d;
    ps[256] = zq.x * zq.x + zq.y * zq.y;
  } else {
    float2 z = ZB[t], u = ZB[512 - t];
    float Er = 0.5f * (z.x + u.x), Ei = 0.5f * (z.y - u.y);
    float Or = 0.5f * (z.y + u.y), Oi = 0.5f * (u.x - z.x);
    float2 w = UP[t];
    float S = w.x * Or + w.y * Oi;
    float T = w.x * Oi - w.y * Or;
    float re1 = Er + S, im1 = Ei + T;
    float re2 = Er - S, im2 = T - Ei;
    ps[t] = re1 * re1 + im1 * im1;
    ps[512 - t] = re2 * re2 + im2 * im2;
  }
  __syncthreads();

  // ---- DC correction (only k < f0/RATE <= 32 matter)
  {
    float rep = 0.f;
    bool act = (t < 40);
    float kf = (float)t;
    if (act) {
      float pos = f0v / RATE - kf;
      int lo = (int)floorf(pos);
      lo = min(max(lo, 0), 511);
      float fr = pos - (float)lo;
      rep = ps[lo] * (1.0f - fr) + ps[lo + 1] * fr;
    }
    __syncthreads();
    if (act && kf * RATE < f0v) ps[t] += rep;
  }
  __syncthreads();

  // ---- linear smoothing: cumsum of mirrored extension (641 vals), then interp
  {
    const int ebase = 3 * t;
    float e0 = 0.f, e1 = 0.f, e2 = 0.f;
    {
      int e = ebase;
      if (e < 641)     { int j = e - 64;     j = j < 0 ? -j : j; if (j > 512) j = 1024 - j; e0 = ps[j]; }
      if (e + 1 < 641) { int j = e + 1 - 64; j = j < 0 ? -j : j; if (j > 512) j = 1024 - j; e1 = ps[j]; }
      if (e + 2 < 641) { int j = e + 2 - 64; j = j < 0 ? -j : j; if (j > 512) j = 1024 - j; e2 = ps[j]; }
    }
    float psum = e0 + e1 + e2;
    float sc = psum;
#pragma unroll
    for (int off = 1; off < 64; off <<= 1) {
      float v = __shfl_up(sc, off);
      if (lane >= off) sc += v;
    }
    if (lane == 63) red[8 + wave] = sc;
    __syncthreads();
    float woff = 0.f;
#pragma unroll
    for (int w2 = 0; w2 < 4; ++w2) woff += (w2 < wave) ? red[8 + w2] : 0.f;
    float run = woff + (sc - psum);    // exclusive prefix for this chunk
    if (t == 0) C[0] = 0.f;
    if (ebase < 641)     { run += e0; C[ebase + 1] = RATE * run; }
    if (ebase + 1 < 641) { run += e1; C[ebase + 2] = RATE * run; }
    if (ebase + 2 < 641) { run += e2; C[ebase + 3] = RATE * run; }
  }
  __syncthreads();

  // ---- interp smoothed spectrum, take log  (overwrite ps with lp)
  {
    const float width = f0v * (2.0f / 3.0f);
    const float hwb = width * (1.0f / (2.0f * RATE));
    const float winv = 1.0f / width;
    float s0, s1, s2 = 1.f;
#pragma unroll
    for (int r = 0; r < 3; ++r) {
      int k = (r == 0) ? t : (r == 1) ? (t + 256) : 512;
      if (r == 2 && t != 0) break;
      float kf = (float)k;
      float qh = kf + hwb + 64.5f, ql = kf - hwb + 64.5f;
      int lh = (int)floorf(qh); lh = min(max(lh, 0), 640);
      int ll = (int)floorf(ql); ll = min(max(ll, 0), 640);
      float fh = qh - (float)lh, fl = ql - (float)ll;
      float vh = C[lh] * (1.f - fh) + C[lh + 1] * fh;
      float vl = C[ll] * (1.f - fl) + C[ll + 1] * fl;
      float v = (vh - vl) * winv;
      if (r == 0) s0 = v; else if (r == 1) s1 = v; else s2 = v;
    }
    ps[t] = __logf(s0);
    ps[t + 256] = __logf(s1);
    if (t == 0) ps[512] = __logf(s2);
  }
  __syncthreads();

  // ---- cepstrum = irfft(lp): FFT of even extension, real part / 1024
  ZA[t] = ps2[t];   // (lp[2t], lp[2t+1]) as one b64
  {
    int idx1 = (2 * t + 512) <= 512 ? (2 * t + 512) : (1024 - (2 * t + 512));
    int idx2 = 1024 - (2 * t + 513);
    ZA[t + 256] = make_float2(ps[idx1], ps[idx2]);
  }
  fft512(ZA, ZB, TW, t);

  // ---- lifter on cepstrum: paired unpack (k, 512-k), write lifted into ps
  {
    const float inv = 1.0f / 1024.0f;
    if (t == 0) {
      float2 z0 = ZB[0];
      float2 zq = ZB[256];
      ps[0]   = (z0.x + z0.y) * inv;                       // lift(0) == 1
      ps[256] = zq.x * inv * lift_f(f0v, 256);
      ps[512] = (z0.x - z0.y) * inv * lift_f(f0v, 512);
    } else {
      float2 z = ZB[t], u = ZB[512 - t];
      float Er = 0.5f * (z.x + u.x);
      float Or = 0.5f * (z.y + u.y), Oi = 0.5f * (u.x - z.x);
      float2 w = UP[t];
      float S = w.x * Or + w.y * Oi;
      ps[t]       = (Er + S) * inv * lift_f(f0v, t);
      ps[512 - t] = (Er - S) * inv * lift_f(f0v, 512 - t);
    }
  }
  __syncthreads();

  // ---- final hfft = 1024 * irfft(lifted): FFT of even extension, real part
  ZA[t] = ps2[t];
  {
    int idx1 = (2 * t + 512) <= 512 ? (2 * t + 512) : (1024 - (2 * t + 512));
    int idx2 = 1024 - (2 * t + 513);
    ZA[t + 256] = make_float2(ps[idx1], ps[idx2]);
  }
  fft512(ZA, ZB, TW, t);

  // ---- epilogue: paired unpack stores
  {
    size_t ob = (size_t)blk * 513;
    if (t == 0) {
      float2 z0 = ZB[0];
      float2 zq = ZB[256];
      out[ob]       = z0.x + z0.y;
      out[ob + 256] = zq.x;
      out[ob + 512] = z0.x - z0.y;
    } else {
      float2 z = ZB[t], u = ZB[512 - t];
      float Er = 0.5f * (z.x + u.x);
      float Or = 0.5f * (z.y + u.y), Oi = 0.5f * (u.x - z.x);
      float2 w = UP[t];
      float S = w.x * Or + w.y * Oi;
      out[ob + t]       = Er + S;
      out[ob + 512 - t] = Er - S;
    }
  }
}

extern "C" void kernel_launch(void* const* d_in, const int* in_sizes, int n_in,
                              void* d_out, int out_size, void* d_ws, size_t ws_size,
                              hipStream_t stream) {
  (void)n_in; (void)out_size;
  const float* x  = (const float*)d_in[0];
  const float* f0 = (const float*)d_in[1];
  float* out = (float*)d_out;
  // in_sizes[0] = B*T, in_sizes[1] = B*N with N = T/80 + 1  =>  B = in_sizes[1] - in_sizes[0]/80
  int B = in_sizes[1] - in_sizes[0] / 80;
  if (B < 1) B = 1;
  int Tlen = in_sizes[0] / B;
  int Nfr  = in_sizes[1] / B;

  float2* tw = nullptr;
  if (d_ws && ws_size >= 1538 * sizeof(float)) {
    tw = (float2*)d_ws;
    hipLaunchKernelGGL(init_tables, dim3(4), dim3(256), 0, stream, tw);
  }
  hipLaunchKernelGGL(cheaptrick_kernel, dim3(in_sizes[1]), dim3(256), 0, stream,
                     x, f0, out, Tlen, Nfr, (const float2*)tw);
}